// Round 5
// baseline (464.325 us; speedup 1.0000x reference)
//
#include <hip/hip_runtime.h>
#include <hip/hip_bf16.h>

#define NN 8192
#define FIN 256
#define FOUT 64

// K1: Wh = H@W + bW; s = Wh.a1 + a_b; t = Wh.a2; exps + interleaved PP=(e^t, e^.01t).
__global__ __launch_bounds__(256) void k1_proj(
    const float* __restrict__ H, const float* __restrict__ W,
    const float* __restrict__ bW, const float* __restrict__ aw,
    const float* __restrict__ ab,
    float* __restrict__ Wh, float* __restrict__ s_src, float* __restrict__ t_tar,
    float* __restrict__ E1, float* __restrict__ E2, float* __restrict__ PP)
{
    __shared__ float Hs[16 * FIN];
    int tid = threadIdx.x;
    int i0 = blockIdx.x * 16;
    const float4* Hv = (const float4*)(H + (size_t)i0 * FIN);
    float4* Hsv = (float4*)Hs;
    for (int idx = tid; idx < 16 * FIN / 4; idx += 256) Hsv[idx] = Hv[idx];
    __syncthreads();
    int f = tid & 63, sub = tid >> 6;
    float a1f = aw[f], a2f = aw[64 + f];
    float b = bW[f];
    float acc0 = b, acc1 = b, acc2 = b, acc3 = b;
    for (int k = 0; k < FIN; ++k) {
        float w = W[k * FOUT + f];
        acc0 += Hs[(sub     ) * FIN + k] * w;
        acc1 += Hs[(sub +  4) * FIN + k] * w;
        acc2 += Hs[(sub +  8) * FIN + k] * w;
        acc3 += Hs[(sub + 12) * FIN + k] * w;
    }
    float accs[4] = {acc0, acc1, acc2, acc3};
    #pragma unroll
    for (int q = 0; q < 4; ++q) {
        int i = i0 + sub + 4 * q;
        float a = accs[q];
        Wh[(size_t)i * FOUT + f] = a;
        float v1 = a * a1f, v2 = a * a2f;
        #pragma unroll
        for (int o = 32; o > 0; o >>= 1) {
            v1 += __shfl_xor(v1, o);
            v2 += __shfl_xor(v2, o);
        }
        if (f == 0) {
            float s = v1 + ab[0];
            float t = v2;
            s_src[i] = s; t_tar[i] = t;
            E1[i] = __expf(s); E2[i] = __expf(0.01f * s);
            PP[2 * i]     = __expf(t);
            PP[2 * i + 1] = __expf(0.01f * t);
        }
    }
}

// K24: heterogeneous blocks, tiny static LDS (256 B) so denom blocks keep occupancy.
//  b < 1024 : denom rows — streams A (268 MB) with int4, 8 rows/block.
//             denom[i] = E1_i*Σ_{adj,cond}P1_j + E2_i*Σ_{adj,!cond}P2_j,
//             cond = (s_i+t_j>=0) <=> E1_i*P1_j >= 1.
//  b >= 1024: rank — 256 blocks × 32 nodes (8/wave): rank of t_g (ties by index)
//             and k_g = #{j : t_j < -s_g}; t read via L1/L2 (32 KB, cached).
__global__ __launch_bounds__(256) void k24(
    const int* __restrict__ A, const float* __restrict__ PP,
    const float* __restrict__ E1, const float* __restrict__ E2,
    const float* __restrict__ t_tar, const float* __restrict__ s_src,
    float* __restrict__ denom, int* __restrict__ sorted_idx, int* __restrict__ kidx)
{
    __shared__ float red[64];
    int tid = threadIdx.x;
    int b = blockIdx.x;
    if (b < 1024) {
        int i0 = b * 8;
        float e1r[8], accA[8], accB[8];
        #pragma unroll
        for (int r = 0; r < 8; ++r) { e1r[r] = E1[i0 + r]; accA[r] = 0.f; accB[r] = 0.f; }
        const float4* PPv = (const float4*)PP;
        for (int jv = tid; jv < NN / 4; jv += 256) {
            float4 ppA = PPv[2 * jv];       // P1[j],P2[j],P1[j+1],P2[j+1]
            float4 ppB = PPv[2 * jv + 1];
            #pragma unroll
            for (int r = 0; r < 8; ++r) {
                const int4 a4 = *(const int4*)(A + (size_t)(i0 + r) * NN + jv * 4);
                float e1 = e1r[r];
                {
                    bool c = e1 * ppA.x >= 1.0f;
                    float af = (float)a4.x;
                    accA[r] += af * (c ? ppA.x : 0.0f);
                    accB[r] += af * (c ? 0.0f : ppA.y);
                }
                {
                    bool c = e1 * ppA.z >= 1.0f;
                    float af = (float)a4.y;
                    accA[r] += af * (c ? ppA.z : 0.0f);
                    accB[r] += af * (c ? 0.0f : ppA.w);
                }
                {
                    bool c = e1 * ppB.x >= 1.0f;
                    float af = (float)a4.z;
                    accA[r] += af * (c ? ppB.x : 0.0f);
                    accB[r] += af * (c ? 0.0f : ppB.y);
                }
                {
                    bool c = e1 * ppB.z >= 1.0f;
                    float af = (float)a4.w;
                    accA[r] += af * (c ? ppB.z : 0.0f);
                    accB[r] += af * (c ? 0.0f : ppB.w);
                }
            }
        }
        #pragma unroll
        for (int r = 0; r < 8; ++r) {
            #pragma unroll
            for (int o = 32; o > 0; o >>= 1) {
                accA[r] += __shfl_xor(accA[r], o);
                accB[r] += __shfl_xor(accB[r], o);
            }
        }
        int wv = tid >> 6;
        if ((tid & 63) == 0) {
            #pragma unroll
            for (int r = 0; r < 8; ++r) {
                red[(wv * 8 + r) * 2]     = accA[r];
                red[(wv * 8 + r) * 2 + 1] = accB[r];
            }
        }
        __syncthreads();
        if (tid < 8) {
            float sA = red[tid * 2]      + red[(8 + tid) * 2]      + red[(16 + tid) * 2]      + red[(24 + tid) * 2];
            float sB = red[tid * 2 + 1]  + red[(8 + tid) * 2 + 1]  + red[(16 + tid) * 2 + 1]  + red[(24 + tid) * 2 + 1];
            denom[i0 + tid] = E1[i0 + tid] * sA + E2[i0 + tid] * sB;
        }
    } else {
        int rb = b - 1024;              // 0..255, 32 nodes each
        int lane = tid & 63, wv = tid >> 6;
        int g0 = rb * 32 + wv * 8;      // 8 nodes per wave
        float tj[8], thr[8];
        int rank[8], kc[8];
        #pragma unroll
        for (int q = 0; q < 8; ++q) {
            tj[q] = t_tar[g0 + q]; thr[q] = -s_src[g0 + q];
            rank[q] = 0; kc[q] = 0;
        }
        for (int k = lane; k < NN; k += 64) {
            float tk = t_tar[k];
            #pragma unroll
            for (int q = 0; q < 8; ++q) {
                int g = g0 + q;
                rank[q] += (tk < tj[q] || (tk == tj[q] && k < g)) ? 1 : 0;
                kc[q]   += (tk < thr[q]) ? 1 : 0;
            }
        }
        #pragma unroll
        for (int q = 0; q < 8; ++q) {
            #pragma unroll
            for (int o = 32; o > 0; o >>= 1) {
                rank[q] += __shfl_xor(rank[q], o);
                kc[q]   += __shfl_xor(kc[q], o);
            }
        }
        if (lane == 0) {
            #pragma unroll
            for (int q = 0; q < 8; ++q) {
                sorted_idx[rank[q]] = g0 + q;
                kidx[g0 + q] = kc[q];
            }
        }
    }
}

// K3a: per-chunk (32 m's) totals of P1*Wh and P2*Wh in sorted order. 4 chunks/block.
__global__ __launch_bounds__(256) void k3a_tots(
    const float* __restrict__ Wh, const float* __restrict__ PP,
    const int* __restrict__ sorted_idx,
    float* __restrict__ tots1, float* __restrict__ tots2)
{
    int c = blockIdx.x * 4 + (threadIdx.x >> 6);
    int f = threadIdx.x & 63;
    float t1 = 0.f, t2 = 0.f;
    int m0 = c * 32;
    #pragma unroll 8
    for (int m = m0; m < m0 + 32; ++m) {
        int sj = sorted_idx[m];
        float wh = Wh[(size_t)sj * 64 + f];
        t1 += PP[2 * sj]     * wh;
        t2 += PP[2 * sj + 1] * wh;
    }
    tots1[c * 64 + f] = t1; tots2[c * 64 + f] = t2;
}

// K3b: scan 256 chunk totals -> off2[c] = Σ_{c'<c} tots2, off1[c] = Σ_{c'>c} tots1.
// off2[256] = grand total2 (for k==NN); off1[256] = 0.
__global__ __launch_bounds__(1024) void k3b_scan(
    const float* __restrict__ tots1, const float* __restrict__ tots2,
    float* __restrict__ off1, float* __restrict__ off2)
{
    __shared__ float w1[16 * 64], w2[16 * 64];
    int tid = threadIdx.x, f = tid & 63, wv = tid >> 6;
    int c0 = wv * 16;
    float s1 = 0.f, s2 = 0.f;
    for (int c = c0; c < c0 + 16; ++c) { s1 += tots1[c * 64 + f]; s2 += tots2[c * 64 + f]; }
    w1[wv * 64 + f] = s1; w2[wv * 64 + f] = s2;
    __syncthreads();
    float o2 = 0.f;
    #pragma unroll
    for (int w = 0; w < 16; ++w) if (w < wv) o2 += w2[w * 64 + f];
    float run2 = o2;
    for (int c = c0; c < c0 + 16; ++c) { off2[c * 64 + f] = run2; run2 += tots2[c * 64 + f]; }
    if (wv == 15) off2[256 * 64 + f] = run2;
    float o1 = 0.f;
    #pragma unroll
    for (int w = 0; w < 16; ++w) if (w > wv) o1 += w1[w * 64 + f];
    float run1 = o1;
    for (int c = c0 + 15; c >= c0; --c) { off1[c * 64 + f] = run1; run1 += tots1[c * 64 + f]; }
    if (tid < 64) off1[256 * 64 + tid] = 0.f;
}

// K5: reconstruct pre2[k_i]/suf1[k_i] from chunk offsets + <=32-entry walk, then
// out[i][f] = sigmoid( (E1_i*suf + E2_i*pre) / denom[i] ).  4 nodes/block (1/wave).
__global__ __launch_bounds__(256) void k5_out(
    const float* __restrict__ Wh, const float* __restrict__ PP,
    const int* __restrict__ sorted_idx,
    const float* __restrict__ off1, const float* __restrict__ off2,
    const int* __restrict__ kidx, const float* __restrict__ E1,
    const float* __restrict__ E2, const float* __restrict__ denom,
    float* __restrict__ out)
{
    int tid = threadIdx.x;
    int f = tid & 63, wv = tid >> 6;
    int i = blockIdx.x * 4 + wv;
    int k = kidx[i];
    int c = k >> 5, r = k & 31;
    float pre = off2[c * 64 + f];
    float suf = off1[c * 64 + f];
    if (c < 256) {
        int m0 = c * 32;
        #pragma unroll 8
        for (int q = 0; q < 32; ++q) {
            int sj = sorted_idx[m0 + q];
            float wh = Wh[(size_t)sj * 64 + f];
            if (q < r) pre += PP[2 * sj + 1] * wh;
            else       suf += PP[2 * sj] * wh;
        }
    }
    float num = E1[i] * suf + E2[i] * pre;
    float x = num / denom[i];
    out[(size_t)i * 64 + f] = 1.0f / (1.0f + __expf(-x));
}

extern "C" void kernel_launch(void* const* d_in, const int* in_sizes, int n_in,
                              void* d_out, int out_size, void* d_ws, size_t ws_size,
                              hipStream_t stream) {
    const float* H  = (const float*)d_in[0];
    const int*   A  = (const int*)d_in[1];
    const float* W  = (const float*)d_in[2];
    const float* bW = (const float*)d_in[3];
    const float* aw = (const float*)d_in[4];
    const float* ab = (const float*)d_in[5];
    float* out = (float*)d_out;

    float* ws    = (float*)d_ws;
    float* Wh    = ws;                    // 524288
    float* s_src = Wh + 524288;           // 8192
    float* t_tar = s_src + 8192;          // 8192
    float* E1    = t_tar + 8192;          // 8192
    float* E2    = E1 + 8192;             // 8192
    float* PP    = E2 + 8192;             // 16384
    float* denom = PP + 16384;            // 8192
    float* tots1 = denom + 8192;          // 16384 (256*64)
    float* tots2 = tots1 + 16384;         // 16384
    float* off1  = tots2 + 16384;         // 16448 (257*64)
    float* off2  = off1 + 16448;          // 16448
    int* sorted_idx = (int*)(off2 + 16448);   // 8192 ints
    int* kidx       = sorted_idx + 8192;      // 8192 ints

    hipLaunchKernelGGL(k1_proj, dim3(512), dim3(256), 0, stream,
                       H, W, bW, aw, ab, Wh, s_src, t_tar, E1, E2, PP);
    hipLaunchKernelGGL(k24, dim3(1280), dim3(256), 0, stream,
                       A, PP, E1, E2, t_tar, s_src, denom, sorted_idx, kidx);
    hipLaunchKernelGGL(k3a_tots, dim3(64), dim3(256), 0, stream,
                       Wh, PP, sorted_idx, tots1, tots2);
    hipLaunchKernelGGL(k3b_scan, dim3(1), dim3(1024), 0, stream,
                       tots1, tots2, off1, off2);
    hipLaunchKernelGGL(k5_out, dim3(2048), dim3(256), 0, stream,
                       Wh, PP, sorted_idx, off1, off2, kidx, E1, E2, denom, out);
}

// Round 6
// 424.712 us; speedup vs baseline: 1.0933x; 1.0933x over previous
//
#include <hip/hip_runtime.h>
#include <hip/hip_bf16.h>

#define NN 8192
#define FIN 256
#define FOUT 64

// K1: Wh = H@W + bW; s = Wh.a1 + a_b; t = Wh.a2; exps + interleaved PP=(e^t, e^.01t).
__global__ __launch_bounds__(256) void k1_proj(
    const float* __restrict__ H, const float* __restrict__ W,
    const float* __restrict__ bW, const float* __restrict__ aw,
    const float* __restrict__ ab,
    float* __restrict__ Wh, float* __restrict__ s_src, float* __restrict__ t_tar,
    float* __restrict__ E1, float* __restrict__ E2, float* __restrict__ PP)
{
    __shared__ float Hs[16 * FIN];
    int tid = threadIdx.x;
    int i0 = blockIdx.x * 16;
    const float4* Hv = (const float4*)(H + (size_t)i0 * FIN);
    float4* Hsv = (float4*)Hs;
    for (int idx = tid; idx < 16 * FIN / 4; idx += 256) Hsv[idx] = Hv[idx];
    __syncthreads();
    int f = tid & 63, sub = tid >> 6;
    float a1f = aw[f], a2f = aw[64 + f];
    float b = bW[f];
    float acc0 = b, acc1 = b, acc2 = b, acc3 = b;
    for (int k = 0; k < FIN; ++k) {
        float w = W[k * FOUT + f];
        acc0 += Hs[(sub     ) * FIN + k] * w;
        acc1 += Hs[(sub +  4) * FIN + k] * w;
        acc2 += Hs[(sub +  8) * FIN + k] * w;
        acc3 += Hs[(sub + 12) * FIN + k] * w;
    }
    float accs[4] = {acc0, acc1, acc2, acc3};
    #pragma unroll
    for (int q = 0; q < 4; ++q) {
        int i = i0 + sub + 4 * q;
        float a = accs[q];
        Wh[(size_t)i * FOUT + f] = a;
        float v1 = a * a1f, v2 = a * a2f;
        #pragma unroll
        for (int o = 32; o > 0; o >>= 1) {
            v1 += __shfl_xor(v1, o);
            v2 += __shfl_xor(v2, o);
        }
        if (f == 0) {
            float s = v1 + ab[0];
            float t = v2;
            s_src[i] = s; t_tar[i] = t;
            E1[i] = __expf(s); E2[i] = __expf(0.01f * s);
            PP[2 * i]     = __expf(t);
            PP[2 * i + 1] = __expf(0.01f * t);
        }
    }
}

// K2: one wave per node g (4/block). 64 lanes split the 8192 t-values (LDS-staged),
// butterfly-reduce rank (ties by index) and threshold count k_g = #{j : t_j < -s_g}.
__global__ __launch_bounds__(256) void k2_rank(
    const float* __restrict__ t_tar, const float* __restrict__ s_src,
    int* __restrict__ sorted_idx, int* __restrict__ kidx)
{
    __shared__ float Ts[NN];
    int tid = threadIdx.x;
    const float4* tv = (const float4*)t_tar;
    float4* Tsv = (float4*)Ts;
    for (int idx = tid; idx < NN / 4; idx += 256) Tsv[idx] = tv[idx];
    __syncthreads();
    int wv = tid >> 6, lane = tid & 63;
    int g = blockIdx.x * 4 + wv;
    float tj = Ts[g];
    float thr = -s_src[g];
    int rank = 0, kc = 0;
    #pragma unroll 4
    for (int k = lane; k < NN; k += 64) {
        float tk = Ts[k];
        rank += (tk < tj || (tk == tj && k < g)) ? 1 : 0;
        kc   += (tk < thr) ? 1 : 0;
    }
    #pragma unroll
    for (int o = 32; o > 0; o >>= 1) {
        rank += __shfl_xor(rank, o);
        kc   += __shfl_xor(kc, o);
    }
    if (lane == 0) { sorted_idx[rank] = g; kidx[g] = kc; }
}

// K3 phase A: per-chunk (32 m's) totals of v1 = P1*Wh and v2 = P2*Wh in sorted order.
__global__ __launch_bounds__(64) void k3a_tots(
    const float* __restrict__ Wh, const float* __restrict__ PP,
    const int* __restrict__ sorted_idx,
    float* __restrict__ tots1, float* __restrict__ tots2)
{
    int c = blockIdx.x, f = threadIdx.x;
    float t1 = 0.f, t2 = 0.f;
    int m0 = c * 32;
    #pragma unroll 8
    for (int m = m0; m < m0 + 32; ++m) {
        int sj = sorted_idx[m];
        float wh = Wh[(size_t)sj * 64 + f];
        t1 += PP[2 * sj]     * wh;
        t2 += PP[2 * sj + 1] * wh;
    }
    tots1[c * 64 + f] = t1; tots2[c * 64 + f] = t2;
}

// K3 phase B: scan 256 chunk totals -> exclusive prefix (off2) / exclusive suffix (off1).
__global__ __launch_bounds__(1024) void k3b_scan(
    const float* __restrict__ tots1, const float* __restrict__ tots2,
    float* __restrict__ off1, float* __restrict__ off2,
    float* __restrict__ pre2, float* __restrict__ suf1)
{
    __shared__ float w1[16 * 64], w2[16 * 64];
    int tid = threadIdx.x, f = tid & 63, wv = tid >> 6;
    int c0 = wv * 16;
    float s1 = 0.f, s2 = 0.f;
    for (int c = c0; c < c0 + 16; ++c) { s1 += tots1[c * 64 + f]; s2 += tots2[c * 64 + f]; }
    w1[wv * 64 + f] = s1; w2[wv * 64 + f] = s2;
    __syncthreads();
    float o2 = 0.f;
    #pragma unroll
    for (int w = 0; w < 16; ++w) if (w < wv) o2 += w2[w * 64 + f];
    float run2 = o2;
    for (int c = c0; c < c0 + 16; ++c) { off2[c * 64 + f] = run2; run2 += tots2[c * 64 + f]; }
    if (wv == 15) pre2[(size_t)NN * 64 + f] = run2;   // full prefix total
    float o1 = 0.f;
    #pragma unroll
    for (int w = 0; w < 16; ++w) if (w > wv) o1 += w1[w * 64 + f];
    float run1 = o1;
    for (int c = c0 + 15; c >= c0; --c) { off1[c * 64 + f] = run1; run1 += tots1[c * 64 + f]; }
    if (tid < 64) suf1[(size_t)NN * 64 + tid] = 0.f;
}

// K3 phase C: emit pre2/suf1 within each chunk from the offsets.
__global__ __launch_bounds__(64) void k3c_emit(
    const float* __restrict__ Wh, const float* __restrict__ PP,
    const int* __restrict__ sorted_idx,
    const float* __restrict__ off1, const float* __restrict__ off2,
    float* __restrict__ pre2, float* __restrict__ suf1)
{
    int c = blockIdx.x, f = threadIdx.x;
    int m0 = c * 32;
    float whr[32], p1r[32], p2r[32];
    #pragma unroll
    for (int q = 0; q < 32; ++q) {
        int sj = sorted_idx[m0 + q];
        whr[q] = Wh[(size_t)sj * 64 + f];
        p1r[q] = PP[2 * sj]; p2r[q] = PP[2 * sj + 1];
    }
    float run2 = off2[c * 64 + f];
    #pragma unroll
    for (int q = 0; q < 32; ++q) {
        pre2[(size_t)(m0 + q) * 64 + f] = run2;
        run2 += p2r[q] * whr[q];
    }
    float run1 = off1[c * 64 + f];
    #pragma unroll
    for (int q = 31; q >= 0; --q) {
        run1 += p1r[q] * whr[q];
        suf1[(size_t)(m0 + q) * 64 + f] = run1;
    }
}

// K4 v3: ONE ROW PER BLOCK — contiguous 32 KB stream per block, 8192 blocks.
// denom[i] = E1_i * Σ_{adj,cond} P1_j + E2_i * Σ_{adj,!cond} P2_j,
// cond = (s_i + t_j >= 0)  <=>  E1_i * P1_j >= 1 (exp monotone, boundary-continuous).
__global__ __launch_bounds__(256) void k4_denom(
    const int* __restrict__ A, const float* __restrict__ PP,
    const float* __restrict__ E1, const float* __restrict__ E2,
    float* __restrict__ denom)
{
    __shared__ float red[8];
    int tid = threadIdx.x;
    int i = blockIdx.x;
    float e1 = E1[i];
    float accA = 0.f, accB = 0.f;
    const float4* PPv = (const float4*)PP;
    const int4* Av = (const int4*)(A + (size_t)i * NN);
    #pragma unroll 2
    for (int jv = tid; jv < NN / 4; jv += 256) {
        int4 a4 = Av[jv];
        float4 ppA = PPv[2 * jv];       // P1[j],P2[j],P1[j+1],P2[j+1]
        float4 ppB = PPv[2 * jv + 1];   // P1[j+2],P2[j+2],P1[j+3],P2[j+3]
        {
            bool c = e1 * ppA.x >= 1.0f;
            float af = (float)a4.x;
            accA += af * (c ? ppA.x : 0.0f);
            accB += af * (c ? 0.0f : ppA.y);
        }
        {
            bool c = e1 * ppA.z >= 1.0f;
            float af = (float)a4.y;
            accA += af * (c ? ppA.z : 0.0f);
            accB += af * (c ? 0.0f : ppA.w);
        }
        {
            bool c = e1 * ppB.x >= 1.0f;
            float af = (float)a4.z;
            accA += af * (c ? ppB.x : 0.0f);
            accB += af * (c ? 0.0f : ppB.y);
        }
        {
            bool c = e1 * ppB.z >= 1.0f;
            float af = (float)a4.w;
            accA += af * (c ? ppB.z : 0.0f);
            accB += af * (c ? 0.0f : ppB.w);
        }
    }
    #pragma unroll
    for (int o = 32; o > 0; o >>= 1) {
        accA += __shfl_xor(accA, o);
        accB += __shfl_xor(accB, o);
    }
    int wv = tid >> 6;
    if ((tid & 63) == 0) { red[wv * 2] = accA; red[wv * 2 + 1] = accB; }
    __syncthreads();
    if (tid == 0) {
        float sA = red[0] + red[2] + red[4] + red[6];
        float sB = red[1] + red[3] + red[5] + red[7];
        denom[i] = e1 * sA + E2[i] * sB;
    }
}

// K5: out[i][f] = sigmoid( (E1_i*suf1[k_i][f] + E2_i*pre2[k_i][f]) / denom[i] )
__global__ __launch_bounds__(256) void k5_out(
    const float* __restrict__ suf1, const float* __restrict__ pre2,
    const int* __restrict__ kidx, const float* __restrict__ E1,
    const float* __restrict__ E2, const float* __restrict__ denom,
    float* __restrict__ out)
{
    int tid = threadIdx.x;
    int f = tid & 63, sub = tid >> 6;
    int i = blockIdx.x * 4 + sub;
    int k = kidx[i];
    float num = E1[i] * suf1[(size_t)k * 64 + f] + E2[i] * pre2[(size_t)k * 64 + f];
    float x = num / denom[i];
    out[(size_t)i * 64 + f] = 1.0f / (1.0f + __expf(-x));
}

extern "C" void kernel_launch(void* const* d_in, const int* in_sizes, int n_in,
                              void* d_out, int out_size, void* d_ws, size_t ws_size,
                              hipStream_t stream) {
    const float* H  = (const float*)d_in[0];
    const int*   A  = (const int*)d_in[1];
    const float* W  = (const float*)d_in[2];
    const float* bW = (const float*)d_in[3];
    const float* aw = (const float*)d_in[4];
    const float* ab = (const float*)d_in[5];
    float* out = (float*)d_out;

    float* ws    = (float*)d_ws;
    float* Wh    = ws;                    // 524288
    float* s_src = Wh + 524288;           // 8192
    float* t_tar = s_src + 8192;          // 8192
    float* E1    = t_tar + 8192;          // 8192
    float* E2    = E1 + 8192;             // 8192
    float* PP    = E2 + 8192;             // 16384
    float* denom = PP + 16384;            // 8192
    float* pre2  = denom + 8192;          // 524352 ((N+1)*64)
    float* suf1  = pre2 + 524352;         // 524352
    float* tots1 = suf1 + 524352;         // 16384 (256*64)
    float* tots2 = tots1 + 16384;         // 16384
    float* off1  = tots2 + 16384;         // 16384
    float* off2  = off1 + 16384;          // 16384
    int* sorted_idx = (int*)(off2 + 16384);   // 8192 ints
    int* kidx       = sorted_idx + 8192;      // 8192 ints

    hipLaunchKernelGGL(k1_proj, dim3(512), dim3(256), 0, stream,
                       H, W, bW, aw, ab, Wh, s_src, t_tar, E1, E2, PP);
    hipLaunchKernelGGL(k2_rank, dim3(2048), dim3(256), 0, stream,
                       t_tar, s_src, sorted_idx, kidx);
    hipLaunchKernelGGL(k3a_tots, dim3(256), dim3(64), 0, stream,
                       Wh, PP, sorted_idx, tots1, tots2);
    hipLaunchKernelGGL(k3b_scan, dim3(1), dim3(1024), 0, stream,
                       tots1, tots2, off1, off2, pre2, suf1);
    hipLaunchKernelGGL(k3c_emit, dim3(256), dim3(64), 0, stream,
                       Wh, PP, sorted_idx, off1, off2, pre2, suf1);
    hipLaunchKernelGGL(k4_denom, dim3(8192), dim3(256), 0, stream,
                       A, PP, E1, E2, denom);
    hipLaunchKernelGGL(k5_out, dim3(2048), dim3(256), 0, stream,
                       suf1, pre2, kidx, E1, E2, denom, out);
}

// Round 7
// 419.186 us; speedup vs baseline: 1.1077x; 1.0132x over previous
//
#include <hip/hip_runtime.h>
#include <hip/hip_bf16.h>

#define NN 8192
#define FIN 256
#define FOUT 64

typedef int iv4 __attribute__((ext_vector_type(4)));

// K0: s,t WITHOUT Wh via rank-1 pullback: u = W·a1, v = W·a2 (256-dim),
// s_i = H_i·u + (bW·a1 + a_b), t_i = H_i·v + bW·a2. Then E1/E2/PP exps.
// 512 blocks × 16 nodes (4 waves × 4 nodes, 64-lane dots).
__global__ __launch_bounds__(256) void k0_st(
    const float* __restrict__ H, const float* __restrict__ W,
    const float* __restrict__ bW, const float* __restrict__ aw,
    const float* __restrict__ ab,
    float* __restrict__ s_src, float* __restrict__ t_tar,
    float* __restrict__ E1, float* __restrict__ E2, float* __restrict__ PP)
{
    __shared__ float us[FIN], vs[FIN];
    int tid = threadIdx.x;
    // u[k], v[k]: one k per thread, 64 MACs each (W row k is contiguous).
    float u = 0.f, v = 0.f;
    const float4* Wv = (const float4*)(W + tid * FOUT);
    #pragma unroll
    for (int fq = 0; fq < FOUT / 4; ++fq) {
        float4 w4  = Wv[fq];
        float4 a14 = ((const float4*)aw)[fq];
        float4 a24 = ((const float4*)(aw + FOUT))[fq];
        u += w4.x * a14.x + w4.y * a14.y + w4.z * a14.z + w4.w * a14.w;
        v += w4.x * a24.x + w4.y * a24.y + w4.z * a24.z + w4.w * a24.w;
    }
    us[tid] = u; vs[tid] = v;
    // bias constants (redundant per-thread, trivial; bW is cached)
    float cb1 = ab[0], cb2 = 0.f;
    #pragma unroll 8
    for (int f = 0; f < FOUT; ++f) {
        float bwf = bW[f];
        cb1 += bwf * aw[f];
        cb2 += bwf * aw[FOUT + f];
    }
    __syncthreads();
    int lane = tid & 63, wv = tid >> 6;
    int i0 = blockIdx.x * 16 + wv * 4;
    #pragma unroll
    for (int q = 0; q < 4; ++q) {
        int i = i0 + q;
        const float* Hr = H + (size_t)i * FIN;
        float sv = 0.f, tv = 0.f;
        #pragma unroll
        for (int m = 0; m < 4; ++m) {
            float h = Hr[m * 64 + lane];
            sv += h * us[m * 64 + lane];
            tv += h * vs[m * 64 + lane];
        }
        #pragma unroll
        for (int o = 32; o > 0; o >>= 1) {
            sv += __shfl_xor(sv, o);
            tv += __shfl_xor(tv, o);
        }
        if (lane == 0) {
            float s = sv + cb1, t = tv + cb2;
            s_src[i] = s; t_tar[i] = t;
            E1[i] = __expf(s); E2[i] = __expf(0.01f * s);
            PP[2 * i]     = __expf(t);
            PP[2 * i + 1] = __expf(0.01f * t);
        }
    }
}

// MEGA: heterogeneous blocks, all dependent only on k0 outputs + raw inputs.
//  b < 512  : Wh GEMM (k1 minus scores) — VALU-heavy, dispatched FIRST so it
//             overlaps the HBM-bound denom majority. 16 KB LDS staging.
//  512..767 : rank — 32 nodes/block (8/wave): rank of t_g (ties by index) and
//             k_g = #{j : t_j < -s_g}; t/s read via L2 (kept warm by nt A loads).
//  b >= 768 : denom row i = b-768 — one contiguous 32 KB A row per block,
//             NONTEMPORAL loads (stream-once; protects L2 for W/PP/t).
//             denom[i] = E1_i*Σ_{adj,cond}P1_j + E2_i*Σ_{adj,!cond}P2_j,
//             cond = (s_i+t_j>=0) <=> E1_i*P1_j >= 1 (monotone, boundary-cont).
__global__ __launch_bounds__(256) void k_mega(
    const float* __restrict__ H, const float* __restrict__ W,
    const float* __restrict__ bW,
    const int* __restrict__ A, const float* __restrict__ PP,
    const float* __restrict__ E1, const float* __restrict__ E2,
    const float* __restrict__ t_tar, const float* __restrict__ s_src,
    float* __restrict__ Wh, float* __restrict__ denom,
    int* __restrict__ sorted_idx, int* __restrict__ kidx)
{
    __shared__ float sh[16 * FIN];   // 16 KB — keeps 8 blocks/CU (thread-limited)
    int tid = threadIdx.x;
    int b = blockIdx.x;
    if (b < 512) {
        // ---- Wh GEMM ----
        int i0 = b * 16;
        const float4* Hv = (const float4*)(H + (size_t)i0 * FIN);
        float4* shv = (float4*)sh;
        for (int idx = tid; idx < 16 * FIN / 4; idx += 256) shv[idx] = Hv[idx];
        __syncthreads();
        int f = tid & 63, sub = tid >> 6;
        float bb = bW[f];
        float acc0 = bb, acc1 = bb, acc2 = bb, acc3 = bb;
        for (int k = 0; k < FIN; ++k) {
            float w = W[k * FOUT + f];
            acc0 += sh[(sub     ) * FIN + k] * w;
            acc1 += sh[(sub +  4) * FIN + k] * w;
            acc2 += sh[(sub +  8) * FIN + k] * w;
            acc3 += sh[(sub + 12) * FIN + k] * w;
        }
        Wh[(size_t)(i0 + sub     ) * FOUT + f] = acc0;
        Wh[(size_t)(i0 + sub +  4) * FOUT + f] = acc1;
        Wh[(size_t)(i0 + sub +  8) * FOUT + f] = acc2;
        Wh[(size_t)(i0 + sub + 12) * FOUT + f] = acc3;
    } else if (b < 768) {
        // ---- rank ----
        int rb = b - 512;               // 0..255, 32 nodes each
        int lane = tid & 63, wv = tid >> 6;
        int g0 = rb * 32 + wv * 8;      // 8 nodes per wave
        float tj[8], thr[8];
        int rank[8], kc[8];
        #pragma unroll
        for (int q = 0; q < 8; ++q) {
            tj[q] = t_tar[g0 + q]; thr[q] = -s_src[g0 + q];
            rank[q] = 0; kc[q] = 0;
        }
        for (int k = lane; k < NN; k += 64) {
            float tk = t_tar[k];
            #pragma unroll
            for (int q = 0; q < 8; ++q) {
                int g = g0 + q;
                rank[q] += (tk < tj[q] || (tk == tj[q] && k < g)) ? 1 : 0;
                kc[q]   += (tk < thr[q]) ? 1 : 0;
            }
        }
        #pragma unroll
        for (int q = 0; q < 8; ++q) {
            #pragma unroll
            for (int o = 32; o > 0; o >>= 1) {
                rank[q] += __shfl_xor(rank[q], o);
                kc[q]   += __shfl_xor(kc[q], o);
            }
        }
        if (lane == 0) {
            #pragma unroll
            for (int q = 0; q < 8; ++q) {
                sorted_idx[rank[q]] = g0 + q;
                kidx[g0 + q] = kc[q];
            }
        }
    } else {
        // ---- denom row ----
        int i = b - 768;
        float e1 = E1[i];
        float accA = 0.f, accB = 0.f;
        const float4* PPv = (const float4*)PP;
        const iv4* Av = (const iv4*)(A + (size_t)i * NN);
        #pragma unroll 2
        for (int jv = tid; jv < NN / 4; jv += 256) {
            iv4 a4 = __builtin_nontemporal_load(Av + jv);
            float4 ppA = PPv[2 * jv];       // P1[j],P2[j],P1[j+1],P2[j+1]
            float4 ppB = PPv[2 * jv + 1];   // P1[j+2],P2[j+2],P1[j+3],P2[j+3]
            {
                bool c = e1 * ppA.x >= 1.0f;
                float af = (float)a4.x;
                accA += af * (c ? ppA.x : 0.0f);
                accB += af * (c ? 0.0f : ppA.y);
            }
            {
                bool c = e1 * ppA.z >= 1.0f;
                float af = (float)a4.y;
                accA += af * (c ? ppA.z : 0.0f);
                accB += af * (c ? 0.0f : ppA.w);
            }
            {
                bool c = e1 * ppB.x >= 1.0f;
                float af = (float)a4.z;
                accA += af * (c ? ppB.x : 0.0f);
                accB += af * (c ? 0.0f : ppB.y);
            }
            {
                bool c = e1 * ppB.z >= 1.0f;
                float af = (float)a4.w;
                accA += af * (c ? ppB.z : 0.0f);
                accB += af * (c ? 0.0f : ppB.w);
            }
        }
        #pragma unroll
        for (int o = 32; o > 0; o >>= 1) {
            accA += __shfl_xor(accA, o);
            accB += __shfl_xor(accB, o);
        }
        int wv = tid >> 6;
        if ((tid & 63) == 0) { sh[wv * 2] = accA; sh[wv * 2 + 1] = accB; }
        __syncthreads();
        if (tid == 0) {
            float sA = sh[0] + sh[2] + sh[4] + sh[6];
            float sB = sh[1] + sh[3] + sh[5] + sh[7];
            denom[i] = e1 * sA + E2[i] * sB;
        }
    }
}

// K3a: per-chunk (32 m's) totals of P1*Wh and P2*Wh in sorted order.
__global__ __launch_bounds__(64) void k3a_tots(
    const float* __restrict__ Wh, const float* __restrict__ PP,
    const int* __restrict__ sorted_idx,
    float* __restrict__ tots1, float* __restrict__ tots2)
{
    int c = blockIdx.x, f = threadIdx.x;
    float t1 = 0.f, t2 = 0.f;
    int m0 = c * 32;
    #pragma unroll 8
    for (int m = m0; m < m0 + 32; ++m) {
        int sj = sorted_idx[m];
        float wh = Wh[(size_t)sj * 64 + f];
        t1 += PP[2 * sj]     * wh;
        t2 += PP[2 * sj + 1] * wh;
    }
    tots1[c * 64 + f] = t1; tots2[c * 64 + f] = t2;
}

// K3b: scan 256 chunk totals -> exclusive prefix (off2) / exclusive suffix (off1).
__global__ __launch_bounds__(1024) void k3b_scan(
    const float* __restrict__ tots1, const float* __restrict__ tots2,
    float* __restrict__ off1, float* __restrict__ off2,
    float* __restrict__ pre2, float* __restrict__ suf1)
{
    __shared__ float w1[16 * 64], w2[16 * 64];
    int tid = threadIdx.x, f = tid & 63, wv = tid >> 6;
    int c0 = wv * 16;
    float s1 = 0.f, s2 = 0.f;
    for (int c = c0; c < c0 + 16; ++c) { s1 += tots1[c * 64 + f]; s2 += tots2[c * 64 + f]; }
    w1[wv * 64 + f] = s1; w2[wv * 64 + f] = s2;
    __syncthreads();
    float o2 = 0.f;
    #pragma unroll
    for (int w = 0; w < 16; ++w) if (w < wv) o2 += w2[w * 64 + f];
    float run2 = o2;
    for (int c = c0; c < c0 + 16; ++c) { off2[c * 64 + f] = run2; run2 += tots2[c * 64 + f]; }
    if (wv == 15) pre2[(size_t)NN * 64 + f] = run2;   // full prefix total
    float o1 = 0.f;
    #pragma unroll
    for (int w = 0; w < 16; ++w) if (w > wv) o1 += w1[w * 64 + f];
    float run1 = o1;
    for (int c = c0 + 15; c >= c0; --c) { off1[c * 64 + f] = run1; run1 += tots1[c * 64 + f]; }
    if (tid < 64) suf1[(size_t)NN * 64 + tid] = 0.f;
}

// K3c: emit pre2/suf1 within each chunk from the offsets.
__global__ __launch_bounds__(64) void k3c_emit(
    const float* __restrict__ Wh, const float* __restrict__ PP,
    const int* __restrict__ sorted_idx,
    const float* __restrict__ off1, const float* __restrict__ off2,
    float* __restrict__ pre2, float* __restrict__ suf1)
{
    int c = blockIdx.x, f = threadIdx.x;
    int m0 = c * 32;
    float whr[32], p1r[32], p2r[32];
    #pragma unroll
    for (int q = 0; q < 32; ++q) {
        int sj = sorted_idx[m0 + q];
        whr[q] = Wh[(size_t)sj * 64 + f];
        p1r[q] = PP[2 * sj]; p2r[q] = PP[2 * sj + 1];
    }
    float run2 = off2[c * 64 + f];
    #pragma unroll
    for (int q = 0; q < 32; ++q) {
        pre2[(size_t)(m0 + q) * 64 + f] = run2;
        run2 += p2r[q] * whr[q];
    }
    float run1 = off1[c * 64 + f];
    #pragma unroll
    for (int q = 31; q >= 0; --q) {
        run1 += p1r[q] * whr[q];
        suf1[(size_t)(m0 + q) * 64 + f] = run1;
    }
}

// K5: out[i][f] = sigmoid( (E1_i*suf1[k_i][f] + E2_i*pre2[k_i][f]) / denom[i] )
__global__ __launch_bounds__(256) void k5_out(
    const float* __restrict__ suf1, const float* __restrict__ pre2,
    const int* __restrict__ kidx, const float* __restrict__ E1,
    const float* __restrict__ E2, const float* __restrict__ denom,
    float* __restrict__ out)
{
    int tid = threadIdx.x;
    int f = tid & 63, sub = tid >> 6;
    int i = blockIdx.x * 4 + sub;
    int k = kidx[i];
    float num = E1[i] * suf1[(size_t)k * 64 + f] + E2[i] * pre2[(size_t)k * 64 + f];
    float x = num / denom[i];
    out[(size_t)i * 64 + f] = 1.0f / (1.0f + __expf(-x));
}

extern "C" void kernel_launch(void* const* d_in, const int* in_sizes, int n_in,
                              void* d_out, int out_size, void* d_ws, size_t ws_size,
                              hipStream_t stream) {
    const float* H  = (const float*)d_in[0];
    const int*   A  = (const int*)d_in[1];
    const float* W  = (const float*)d_in[2];
    const float* bW = (const float*)d_in[3];
    const float* aw = (const float*)d_in[4];
    const float* ab = (const float*)d_in[5];
    float* out = (float*)d_out;

    float* ws    = (float*)d_ws;
    float* Wh    = ws;                    // 524288
    float* s_src = Wh + 524288;           // 8192
    float* t_tar = s_src + 8192;          // 8192
    float* E1    = t_tar + 8192;          // 8192
    float* E2    = E1 + 8192;             // 8192
    float* PP    = E2 + 8192;             // 16384
    float* denom = PP + 16384;            // 8192
    float* pre2  = denom + 8192;          // 524352 ((N+1)*64)
    float* suf1  = pre2 + 524352;         // 524352
    float* tots1 = suf1 + 524352;         // 16384 (256*64)
    float* tots2 = tots1 + 16384;         // 16384
    float* off1  = tots2 + 16384;         // 16384
    float* off2  = off1 + 16384;          // 16384
    int* sorted_idx = (int*)(off2 + 16384);   // 8192 ints
    int* kidx       = sorted_idx + 8192;      // 8192 ints

    hipLaunchKernelGGL(k0_st, dim3(512), dim3(256), 0, stream,
                       H, W, bW, aw, ab, s_src, t_tar, E1, E2, PP);
    hipLaunchKernelGGL(k_mega, dim3(8960), dim3(256), 0, stream,
                       H, W, bW, A, PP, E1, E2, t_tar, s_src,
                       Wh, denom, sorted_idx, kidx);
    hipLaunchKernelGGL(k3a_tots, dim3(256), dim3(64), 0, stream,
                       Wh, PP, sorted_idx, tots1, tots2);
    hipLaunchKernelGGL(k3b_scan, dim3(1), dim3(1024), 0, stream,
                       tots1, tots2, off1, off2, pre2, suf1);
    hipLaunchKernelGGL(k3c_emit, dim3(256), dim3(64), 0, stream,
                       Wh, PP, sorted_idx, off1, off2, pre2, suf1);
    hipLaunchKernelGGL(k5_out, dim3(2048), dim3(256), 0, stream,
                       suf1, pre2, kidx, E1, E2, denom, out);
}